// Round 1
// baseline (199.227 us; speedup 1.0000x reference)
//
#include <hip/hip_runtime.h>

#define Bn 8
#define Cc 64
#define CO 64
#define Hh 128
#define Ww 128
#define Kk 9
#define HW (Hh*Ww)

// ---------------- kernel 1: input NCHW -> NHWC ----------------
__global__ __launch_bounds__(256) void transpose_in_kernel(
    const float* __restrict__ in, float* __restrict__ in_t)
{
    __shared__ float tile[64 * 65];
    int bid  = blockIdx.x;          // B*H*2 = 2048
    int xblk = bid & 1;
    int row  = bid >> 1;            // b*H + y
    int y    = row & (Hh - 1);
    int b    = row >> 7;
    int x0   = xblk << 6;
    int t    = threadIdx.x;

    int x  = t & 63;
    int cq = t >> 6;
    const float* src = in + (size_t)b * Cc * HW + (size_t)y * Ww + x0;
#pragma unroll
    for (int i = 0; i < 16; ++i) {
        int c = cq * 16 + i;
        tile[c * 65 + x] = src[(size_t)c * HW + x];   // lanes: x contiguous -> coalesced
    }
    __syncthreads();
    int c2 = t & 63;
    int xq = t >> 6;
    float* dst = in_t + ((size_t)(b * Hh + y) * Ww + x0) * Cc;
#pragma unroll
    for (int i = 0; i < 16; ++i) {
        int xx = xq * 16 + i;
        dst[(size_t)xx * Cc + c2] = tile[c2 * 65 + xx]; // lanes: c contiguous -> coalesced
    }
}

// ---------------- kernel 2: weight [co][c][k] -> [k][c][co] ----------------
__global__ __launch_bounds__(256) void transpose_w_kernel(
    const float* __restrict__ w, float* __restrict__ w_t)
{
    int idx = blockIdx.x * 256 + threadIdx.x;
    if (idx < CO * Cc * Kk) {
        int k   = idx >> 12;          // /4096
        int rem = idx & 4095;
        int c   = rem >> 6;
        int co  = rem & 63;
        w_t[idx] = w[((size_t)co * Cc + c) * Kk + k];
    }
}

// ---------------- kernel 3: fused sample + implicit GEMM ----------------
// block: 256 threads = one (b, y, 64-pixel x-chunk); all 64 output channels.
__global__ __launch_bounds__(256) void dcn_main_kernel(
    const float* __restrict__ in_t,   // [B][H][W][C]
    const float* __restrict__ offm,   // [B][27][H][W]
    const float* __restrict__ w_t,    // [K][C][CO]
    const float* __restrict__ bias,   // [CO]
    float* __restrict__ out)          // [B][CO][H][W]
{
    __shared__ float s_a[64 * 68];        // sampled [c][px], stride 68 (16B-aligned rows)
    __shared__ float s_w[64 * 64];        // weight  [c][co]
    __shared__ float s_cw[4 * Kk * 64];   // corner weights (mask folded) [corner][k][px]
    __shared__ int   s_ci[4 * Kk * 64];   // clamped corner flat index    [corner][k][px]

    int bid  = blockIdx.x;                // 2048
    int xblk = bid & 1;
    int row  = bid >> 1;
    int y    = row & (Hh - 1);
    int b    = row >> 7;
    int x0   = xblk << 6;
    int t    = threadIdx.x;

    const float* offb = offm + (size_t)b * 27 * HW + (size_t)y * Ww + x0;
    const float* inb  = in_t + (size_t)b * HW * Cc;

    // ---- precompute bilinear corner weights/indices for all (k, px) ----
    for (int idx = t; idx < Kk * 64; idx += 256) {
        int k  = idx >> 6;
        int px = idx & 63;
        float dy = offb[(size_t)(2 * k) * HW + px];
        float dx = offb[(size_t)(2 * k + 1) * HW + px];
        float ml = offb[(size_t)(18 + k) * HW + px];
        float m  = 1.0f / (1.0f + __expf(-ml));

        float ys = (float)(y + (k / 3) - 1) + dy;
        float xs = (float)(x0 + px + (k % 3) - 1) + dx;
        float yf = floorf(ys), xf = floorf(xs);
        int y0i = (int)yf, x0i = (int)xf;
        int y1i = y0i + 1, x1i = x0i + 1;
        float wy = ys - yf, wx = xs - xf;

        bool vy0 = (unsigned)y0i < (unsigned)Hh;
        bool vy1 = (unsigned)y1i < (unsigned)Hh;
        bool vx0 = (unsigned)x0i < (unsigned)Ww;
        bool vx1 = (unsigned)x1i < (unsigned)Ww;

        int cy0 = min(max(y0i, 0), Hh - 1);
        int cy1 = min(max(y1i, 0), Hh - 1);
        int cx0 = min(max(x0i, 0), Ww - 1);
        int cx1 = min(max(x1i, 0), Ww - 1);

        float w00 = (vy0 && vx0) ? (1.0f - wy) * (1.0f - wx) * m : 0.0f;
        float w01 = (vy0 && vx1) ? (1.0f - wy) * wx * m : 0.0f;
        float w10 = (vy1 && vx0) ? wy * (1.0f - wx) * m : 0.0f;
        float w11 = (vy1 && vx1) ? wy * wx * m : 0.0f;

        s_cw[0 * Kk * 64 + idx] = w00;  s_ci[0 * Kk * 64 + idx] = cy0 * Ww + cx0;
        s_cw[1 * Kk * 64 + idx] = w01;  s_ci[1 * Kk * 64 + idx] = cy0 * Ww + cx1;
        s_cw[2 * Kk * 64 + idx] = w10;  s_ci[2 * Kk * 64 + idx] = cy1 * Ww + cx0;
        s_cw[3 * Kk * 64 + idx] = w11;  s_ci[3 * Kk * 64 + idx] = cy1 * Ww + cx1;
    }
    __syncthreads();

    float acc[4][4] = {};
    int tx = t & 15;    // co0 = 4*tx
    int ty = t >> 4;    // px0 = 4*ty
    int c_s = t & 63;   // sampling: lane = channel (coalesced gathers)
    int q_s = t >> 6;   // sampling: wave -> pixel quad

    for (int k = 0; k < Kk; ++k) {
        // stage weight slice w_t[k][c][co] -> s_w (coalesced float4)
        {
            const float4* src = (const float4*)(w_t + (size_t)k * 4096);
            float4* dst = (float4*)s_w;
#pragma unroll
            for (int i = 0; i < 4; ++i) dst[t + 256 * i] = src[t + 256 * i];
        }
        // sample: each thread does channel c_s for 16 pixels (4 quads)
#pragma unroll
        for (int i = 0; i < 4; ++i) {
            int q   = q_s + 4 * i;
            int pxb = q << 2;
            float vv[4];
#pragma unroll
            for (int j = 0; j < 4; ++j) {
                int px   = pxb + j;
                int base = (k << 6) + px;
                float v = 0.0f;
#pragma unroll
                for (int cn = 0; cn < 4; ++cn) {
                    int   off = s_ci[cn * Kk * 64 + base];
                    float wgt = s_cw[cn * Kk * 64 + base];
                    v += wgt * inb[(size_t)off * Cc + c_s];   // 256B coalesced per wave
                }
                vv[j] = v;
            }
            *(float4*)&s_a[c_s * 68 + pxb] = make_float4(vv[0], vv[1], vv[2], vv[3]);
        }
        __syncthreads();

        // register-tiled GEMM: acc[px][co] += A[c][px] * W[c][co]
#pragma unroll 4
        for (int c = 0; c < 64; ++c) {
            const float4 av = *(const float4*)&s_a[c * 68 + (ty << 2)];
            const float4 wv = *(const float4*)&s_w[(c << 6) + (tx << 2)];
            acc[0][0] += av.x * wv.x; acc[0][1] += av.x * wv.y; acc[0][2] += av.x * wv.z; acc[0][3] += av.x * wv.w;
            acc[1][0] += av.y * wv.x; acc[1][1] += av.y * wv.y; acc[1][2] += av.y * wv.z; acc[1][3] += av.y * wv.w;
            acc[2][0] += av.z * wv.x; acc[2][1] += av.z * wv.y; acc[2][2] += av.z * wv.z; acc[2][3] += av.z * wv.w;
            acc[3][0] += av.w * wv.x; acc[3][1] += av.w * wv.y; acc[3][2] += av.w * wv.z; acc[3][3] += av.w * wv.w;
        }
        __syncthreads();
    }

    // epilogue: restage through LDS for coalesced output rows
#pragma unroll
    for (int j = 0; j < 4; ++j) {
        *(float4*)&s_a[(4 * tx + j) * 68 + (ty << 2)] =
            make_float4(acc[0][j], acc[1][j], acc[2][j], acc[3][j]);
    }
    __syncthreads();

    int px = t & 63;
    int cg = t >> 6;
    float* outb = out + (size_t)b * CO * HW + (size_t)y * Ww + x0;
#pragma unroll
    for (int r = 0; r < 16; ++r) {
        int co = cg * 16 + r;
        outb[(size_t)co * HW + px] = s_a[co * 68 + px] + bias[co];
    }
}

// ---------------- launcher ----------------
extern "C" void kernel_launch(void* const* d_in, const int* in_sizes, int n_in,
                              void* d_out, int out_size, void* d_ws, size_t ws_size,
                              hipStream_t stream)
{
    const float* in   = (const float*)d_in[0];
    const float* offm = (const float*)d_in[1];
    const float* w    = (const float*)d_in[2];
    const float* bias = (const float*)d_in[3];
    float* out = (float*)d_out;

    float* in_t = (float*)d_ws;                       // 8*128*128*64 f32 = 32 MiB
    float* w_t  = in_t + (size_t)Bn * HW * Cc;        // 9*64*64 f32 = 144 KiB

    transpose_in_kernel<<<Bn * Hh * 2, 256, 0, stream>>>(in, in_t);
    transpose_w_kernel<<<(CO * Cc * Kk + 255) / 256, 256, 0, stream>>>(w, w_t);
    dcn_main_kernel<<<Bn * Hh * 2, 256, 0, stream>>>(in_t, offm, w_t, bias, out);
}

// Round 2
// 172.315 us; speedup vs baseline: 1.1562x; 1.1562x over previous
//
#include <hip/hip_runtime.h>

#define Bn 8
#define Cc 64
#define CO 64
#define Hh 128
#define Ww 128
#define Kk 9
#define HW (Hh*Ww)

typedef __attribute__((ext_vector_type(8))) short bf16x8;
typedef __attribute__((ext_vector_type(4))) float f32x4;

__device__ __forceinline__ short f2bf(float f) {
    unsigned u = __float_as_uint(f);
    u = (u + 0x7FFFu + ((u >> 16) & 1u)) >> 16;   // RNE
    return (short)u;
}

// ---------------- kernel 1: input NCHW -> NHWC (fp32) ----------------
__global__ __launch_bounds__(256) void transpose_in_kernel(
    const float* __restrict__ in, float* __restrict__ in_t)
{
    __shared__ float tile[64 * 65];
    int bid  = blockIdx.x;          // B*H*2 = 2048
    int xblk = bid & 1;
    int row  = bid >> 1;            // b*H + y
    int y    = row & (Hh - 1);
    int b    = row >> 7;
    int x0   = xblk << 6;
    int t    = threadIdx.x;

    int x  = t & 63;
    int cq = t >> 6;
    const float* src = in + (size_t)b * Cc * HW + (size_t)y * Ww + x0;
#pragma unroll
    for (int i = 0; i < 16; ++i) {
        int c = cq * 16 + i;
        tile[c * 65 + x] = src[(size_t)c * HW + x];
    }
    __syncthreads();
    int c2 = t & 63;
    int xq = t >> 6;
    float* dst = in_t + ((size_t)(b * Hh + y) * Ww + x0) * Cc;
#pragma unroll
    for (int i = 0; i < 16; ++i) {
        int xx = xq * 16 + i;
        dst[(size_t)xx * Cc + c2] = tile[c2 * 65 + xx];
    }
}

// ---------------- kernel 2: weight fp32 [co][c][k] -> bf16 [k][co][c] ----------------
__global__ __launch_bounds__(256) void prep_w_kernel(
    const float* __restrict__ w, short* __restrict__ w_t)
{
    int idx = blockIdx.x * 256 + threadIdx.x;
    if (idx < Kk * CO * Cc) {
        int k  = idx >> 12;
        int co = (idx >> 6) & 63;
        int c  = idx & 63;
        w_t[idx] = f2bf(w[((size_t)co * Cc + c) * Kk + k]);
    }
}

// ---------------- kernel 3: fused sample + MFMA implicit GEMM ----------------
// block: 256 threads = (b, y, 64-px x-chunk); all 64 co.
// sampling: lane = px, wave = 16-channel slice. GEMM: wave = 16-px stripe, all co.
__global__ __launch_bounds__(256, 4) void dcn_main_kernel(
    const float* __restrict__ in_t,   // [B][H][W][C] fp32
    const float* __restrict__ offm,   // [B][27][H][W] fp32
    const short* __restrict__ w_t,    // [K][CO][C] bf16
    const float* __restrict__ bias,   // [CO] fp32
    float* __restrict__ out)          // [B][CO][H][W] fp32
{
    __shared__ short s_S[2][64][72];  // sampled bf16 [px][c], pad 72
    __shared__ short s_W[2][64][72];  // weight  bf16 [co][c], pad 72

    int bid  = blockIdx.x;            // 2048
    int xblk = bid & 1;
    int row  = bid >> 1;
    int y    = row & (Hh - 1);
    int b    = row >> 7;
    int x0   = xblk << 6;
    int t    = threadIdx.x;
    int l    = t & 63;                // lane: px for sampling
    int wv   = t >> 6;                // wave 0..3
    int c0   = wv << 4;               // sampling channel slice

    const float* offb = offm + (size_t)b * 27 * HW + (size_t)y * Ww + x0 + l;
    const float* inb  = in_t + (size_t)b * HW * Cc;

    // W staging indices (256 threads cover 64co x 64c)
    int wco = t >> 2;
    int wc0 = (t & 3) << 4;

    f32x4 acc[4] = {{0.f,0.f,0.f,0.f},{0.f,0.f,0.f,0.f},{0.f,0.f,0.f,0.f},{0.f,0.f,0.f,0.f}};
    int lm = l & 15;   // mfma col (px within stripe) / row-within-frag select
    int g  = l >> 4;   // mfma k-chunk group

    // ---- sample kernel-point k into s_S[nb], stage weights k into s_W[nb] ----
    auto stage = [&](int k, int nb) {
        // per-pixel offsets (coalesced; identical across the 4 waves -> L1)
        float dy = offb[(size_t)(2 * k) * HW];
        float dx = offb[(size_t)(2 * k + 1) * HW];
        float ml = offb[(size_t)(18 + k) * HW];
        float m  = __builtin_amdgcn_rcpf(1.0f + __expf(-ml));

        float ys = (float)(y + (k / 3) - 1) + dy;
        float xs = (float)(x0 + l + (k % 3) - 1) + dx;
        float yf = floorf(ys), xf = floorf(xs);
        int y0i = (int)yf, x0i = (int)xf;
        float wy = ys - yf, wx = xs - xf;

        bool vy0 = (unsigned)y0i < (unsigned)Hh;
        bool vy1 = (unsigned)(y0i + 1) < (unsigned)Hh;
        bool vx0 = (unsigned)x0i < (unsigned)Ww;
        bool vx1 = (unsigned)(x0i + 1) < (unsigned)Ww;

        int cy0 = min(max(y0i, 0), Hh - 1);
        int cy1 = min(max(y0i + 1, 0), Hh - 1);
        int cx0 = min(max(x0i, 0), Ww - 1);
        int cx1 = min(max(x0i + 1, 0), Ww - 1);

        float w00 = (vy0 && vx0) ? (1.0f - wy) * (1.0f - wx) * m : 0.0f;
        float w01 = (vy0 && vx1) ? (1.0f - wy) * wx * m : 0.0f;
        float w10 = (vy1 && vx0) ? wy * (1.0f - wx) * m : 0.0f;
        float w11 = (vy1 && vx1) ? wy * wx * m : 0.0f;

        int i00 = cy0 * Ww + cx0, i01 = cy0 * Ww + cx1;
        int i10 = cy1 * Ww + cx0, i11 = cy1 * Ww + cx1;

        float a0=0,a1=0,a2=0,a3=0,a4=0,a5=0,a6=0,a7=0;
        float a8=0,a9=0,a10=0,a11=0,a12=0,a13=0,a14=0,a15=0;

#define ACC_CORNER(IDX, WGT) do { \
        const float4* p = (const float4*)(inb + (size_t)(IDX) * Cc + c0); \
        float4 q0 = p[0], q1 = p[1], q2 = p[2], q3 = p[3]; \
        a0  += (WGT) * q0.x; a1  += (WGT) * q0.y; a2  += (WGT) * q0.z; a3  += (WGT) * q0.w; \
        a4  += (WGT) * q1.x; a5  += (WGT) * q1.y; a6  += (WGT) * q1.z; a7  += (WGT) * q1.w; \
        a8  += (WGT) * q2.x; a9  += (WGT) * q2.y; a10 += (WGT) * q2.z; a11 += (WGT) * q2.w; \
        a12 += (WGT) * q3.x; a13 += (WGT) * q3.y; a14 += (WGT) * q3.z; a15 += (WGT) * q3.w; \
    } while (0)

        ACC_CORNER(i00, w00);
        ACC_CORNER(i01, w01);
        ACC_CORNER(i10, w10);
        ACC_CORNER(i11, w11);
#undef ACC_CORNER

        // pack 16 fp32 -> 16 bf16 -> two b128 LDS writes at S[px][c0..c0+15]
        union { bf16x8 v; short s[8]; } u0, u1;
        u0.s[0]=f2bf(a0);  u0.s[1]=f2bf(a1);  u0.s[2]=f2bf(a2);  u0.s[3]=f2bf(a3);
        u0.s[4]=f2bf(a4);  u0.s[5]=f2bf(a5);  u0.s[6]=f2bf(a6);  u0.s[7]=f2bf(a7);
        u1.s[0]=f2bf(a8);  u1.s[1]=f2bf(a9);  u1.s[2]=f2bf(a10); u1.s[3]=f2bf(a11);
        u1.s[4]=f2bf(a12); u1.s[5]=f2bf(a13); u1.s[6]=f2bf(a14); u1.s[7]=f2bf(a15);
        *(bf16x8*)&s_S[nb][l][c0]     = u0.v;
        *(bf16x8*)&s_S[nb][l][c0 + 8] = u1.v;

        // stage W[k] slice: bf16 [co][c] with pad
        const short* wk = w_t + (size_t)k * (CO * Cc) + 16 * t;
        bf16x8 wv0 = *(const bf16x8*)(wk);
        bf16x8 wv1 = *(const bf16x8*)(wk + 8);
        *(bf16x8*)&s_W[nb][wco][wc0]     = wv0;
        *(bf16x8*)&s_W[nb][wco][wc0 + 8] = wv1;
    };

    stage(0, 0);
    __syncthreads();

    for (int k = 0; k < Kk; ++k) {
        int cb = k & 1;
        if (k < Kk - 1) stage(k + 1, cb ^ 1);

        // GEMM: out[co][px] += W^T[co][c] * S^T[c][px], K=64 per k (2 mfma steps)
        bf16x8 b0 = *(const bf16x8*)&s_S[cb][(wv << 4) + lm][(g << 3)];
        bf16x8 b1 = *(const bf16x8*)&s_S[cb][(wv << 4) + lm][32 + (g << 3)];
#pragma unroll
        for (int f = 0; f < 4; ++f) {
            bf16x8 A0 = *(const bf16x8*)&s_W[cb][(f << 4) + lm][(g << 3)];
            bf16x8 A1 = *(const bf16x8*)&s_W[cb][(f << 4) + lm][32 + (g << 3)];
            acc[f] = __builtin_amdgcn_mfma_f32_16x16x32_bf16(A0, b0, acc[f], 0, 0, 0);
            acc[f] = __builtin_amdgcn_mfma_f32_16x16x32_bf16(A1, b1, acc[f], 0, 0, 0);
        }
        __syncthreads();
    }

    // epilogue: lane l holds D[co = 16f + 4g + r][px = 16wv + lm]
    float* outb = out + (size_t)b * CO * HW + (size_t)y * Ww + x0 + (wv << 4) + lm;
#pragma unroll
    for (int f = 0; f < 4; ++f) {
#pragma unroll
        for (int r = 0; r < 4; ++r) {
            int co = (f << 4) + (g << 2) + r;
            outb[(size_t)co * HW] = acc[f][r] + bias[co];
        }
    }
}

// ---------------- launcher ----------------
extern "C" void kernel_launch(void* const* d_in, const int* in_sizes, int n_in,
                              void* d_out, int out_size, void* d_ws, size_t ws_size,
                              hipStream_t stream)
{
    const float* in   = (const float*)d_in[0];
    const float* offm = (const float*)d_in[1];
    const float* w    = (const float*)d_in[2];
    const float* bias = (const float*)d_in[3];
    float* out = (float*)d_out;

    float* in_t = (float*)d_ws;                         // 8*128*128*64 f32 = 32 MiB
    short* w_t  = (short*)(in_t + (size_t)Bn * HW * Cc); // 9*64*64 bf16 = 72 KiB

    transpose_in_kernel<<<Bn * Hh * 2, 256, 0, stream>>>(in, in_t);
    prep_w_kernel<<<(Kk * CO * Cc + 255) / 256, 256, 0, stream>>>(w, w_t);
    dcn_main_kernel<<<Bn * Hh * 2, 256, 0, stream>>>(in_t, offm, w_t, bias, out);
}

// Round 3
// 97.734 us; speedup vs baseline: 2.0385x; 1.7631x over previous
//
#include <hip/hip_runtime.h>

#define Bn 8
#define Cc 64
#define CO 64
#define Hh 128
#define Ww 128
#define Kk 9
#define HW (Hh*Ww)

typedef __attribute__((ext_vector_type(8))) short bf16x8;
typedef __attribute__((ext_vector_type(4))) float f32x4;

__device__ __forceinline__ short f2bf(float f) {
    unsigned u = __float_as_uint(f);
    u = (u + 0x7FFFu + ((u >> 16) & 1u)) >> 16;   // RNE
    return (short)u;
}
__device__ __forceinline__ float bf2f(short s) {
    return __uint_as_float(((unsigned)(unsigned short)s) << 16);
}

// ---------------- kernel 1: input NCHW fp32 -> NHWC bf16 ----------------
__global__ __launch_bounds__(256) void transpose_in_kernel(
    const float* __restrict__ in, short* __restrict__ in_t)
{
    __shared__ float tile[64 * 65];
    int bid  = blockIdx.x;          // B*H*2 = 2048
    int xblk = bid & 1;
    int row  = bid >> 1;            // b*H + y
    int y    = row & (Hh - 1);
    int b    = row >> 7;
    int x0   = xblk << 6;
    int t    = threadIdx.x;

    int x  = t & 63;
    int cq = t >> 6;
    const float* src = in + (size_t)b * Cc * HW + (size_t)y * Ww + x0;
#pragma unroll
    for (int i = 0; i < 16; ++i) {
        int c = cq * 16 + i;
        tile[c * 65 + x] = src[(size_t)c * HW + x];   // coalesced read
    }
    __syncthreads();
    int c2 = t & 63;
    int xq = t >> 6;
    short* dst = in_t + ((size_t)(b * Hh + y) * Ww + x0) * Cc;
#pragma unroll
    for (int i = 0; i < 16; ++i) {
        int xx = xq * 16 + i;
        dst[(size_t)xx * Cc + c2] = f2bf(tile[c2 * 65 + xx]); // coalesced bf16 write
    }
}

// ---------------- kernel 2: weight fp32 [co][c][k] -> bf16 [k][co][c] ----------------
__global__ __launch_bounds__(256) void prep_w_kernel(
    const float* __restrict__ w, short* __restrict__ w_t)
{
    int idx = blockIdx.x * 256 + threadIdx.x;
    if (idx < Kk * CO * Cc) {
        int k  = idx >> 12;
        int co = (idx >> 6) & 63;
        int c  = idx & 63;
        w_t[idx] = f2bf(w[((size_t)co * Cc + c) * Kk + k]);
    }
}

// ---------------- kernel 3: fused sample + MFMA implicit GEMM ----------------
// block: 256 threads = (b, y, 64-px x-chunk); all 64 co.
// sampling: lane = px, wave = 16-channel slice (bf16 -> 2x16B gathers/corner).
__global__ __launch_bounds__(256, 4) void dcn_main_kernel(
    const short* __restrict__ in_t,   // [B][H][W][C] bf16
    const float* __restrict__ offm,   // [B][27][H][W] fp32
    const short* __restrict__ w_t,    // [K][CO][C] bf16
    const float* __restrict__ bias,   // [CO] fp32
    float* __restrict__ out)          // [B][CO][H][W] fp32
{
    __shared__ short s_S[2][64][72];  // sampled bf16 [px][c], pad 72
    __shared__ short s_W[2][64][72];  // weight  bf16 [co][c], pad 72

    int bid  = blockIdx.x;            // 2048
    int xblk = bid & 1;
    int row  = bid >> 1;
    int y    = row & (Hh - 1);
    int b    = row >> 7;
    int x0   = xblk << 6;
    int t    = threadIdx.x;
    int l    = t & 63;                // lane: px for sampling
    int wv   = t >> 6;                // wave 0..3
    int c0   = wv << 4;               // sampling channel slice

    const float* offb = offm + (size_t)b * 27 * HW + (size_t)y * Ww + x0 + l;
    const short* inb  = in_t + (size_t)b * HW * Cc;

    // W staging indices (256 threads cover 64co x 64c)
    int wco = t >> 2;
    int wc0 = (t & 3) << 4;

    f32x4 acc[4] = {{0.f,0.f,0.f,0.f},{0.f,0.f,0.f,0.f},{0.f,0.f,0.f,0.f},{0.f,0.f,0.f,0.f}};
    int lm = l & 15;   // mfma col select
    int g  = l >> 4;   // mfma k-chunk group

    auto stage = [&](int k, int nb) {
        float dy = offb[(size_t)(2 * k) * HW];
        float dx = offb[(size_t)(2 * k + 1) * HW];
        float ml = offb[(size_t)(18 + k) * HW];
        float m  = __builtin_amdgcn_rcpf(1.0f + __expf(-ml));

        float ys = (float)(y + (k / 3) - 1) + dy;
        float xs = (float)(x0 + l + (k % 3) - 1) + dx;
        float yf = floorf(ys), xf = floorf(xs);
        int y0i = (int)yf, x0i = (int)xf;
        float wy = ys - yf, wx = xs - xf;

        bool vy0 = (unsigned)y0i < (unsigned)Hh;
        bool vy1 = (unsigned)(y0i + 1) < (unsigned)Hh;
        bool vx0 = (unsigned)x0i < (unsigned)Ww;
        bool vx1 = (unsigned)(x0i + 1) < (unsigned)Ww;

        int cy0 = min(max(y0i, 0), Hh - 1);
        int cy1 = min(max(y0i + 1, 0), Hh - 1);
        int cx0 = min(max(x0i, 0), Ww - 1);
        int cx1 = min(max(x0i + 1, 0), Ww - 1);

        float w00 = (vy0 && vx0) ? (1.0f - wy) * (1.0f - wx) * m : 0.0f;
        float w01 = (vy0 && vx1) ? (1.0f - wy) * wx * m : 0.0f;
        float w10 = (vy1 && vx0) ? wy * (1.0f - wx) * m : 0.0f;
        float w11 = (vy1 && vx1) ? wy * wx * m : 0.0f;

        int i00 = cy0 * Ww + cx0, i01 = cy0 * Ww + cx1;
        int i10 = cy1 * Ww + cx0, i11 = cy1 * Ww + cx1;

        float a[16];
#pragma unroll
        for (int j = 0; j < 16; ++j) a[j] = 0.0f;

#define ACC_CORNER(IDX, WGT) do { \
        const bf16x8* p = (const bf16x8*)(inb + (size_t)(IDX) * Cc + c0); \
        union { bf16x8 v; short s[8]; } r0, r1; \
        r0.v = p[0]; r1.v = p[1]; \
        _Pragma("unroll") \
        for (int j = 0; j < 8; ++j) { \
            a[j]     += (WGT) * bf2f(r0.s[j]); \
            a[j + 8] += (WGT) * bf2f(r1.s[j]); \
        } \
    } while (0)

        ACC_CORNER(i00, w00);
        ACC_CORNER(i01, w01);
        ACC_CORNER(i10, w10);
        ACC_CORNER(i11, w11);
#undef ACC_CORNER

        union { bf16x8 v; short s[8]; } u0, u1;
#pragma unroll
        for (int j = 0; j < 8; ++j) { u0.s[j] = f2bf(a[j]); u1.s[j] = f2bf(a[j + 8]); }
        *(bf16x8*)&s_S[nb][l][c0]     = u0.v;
        *(bf16x8*)&s_S[nb][l][c0 + 8] = u1.v;

        const short* wk = w_t + (size_t)k * (CO * Cc) + 16 * t;
        bf16x8 wv0 = *(const bf16x8*)(wk);
        bf16x8 wv1 = *(const bf16x8*)(wk + 8);
        *(bf16x8*)&s_W[nb][wco][wc0]     = wv0;
        *(bf16x8*)&s_W[nb][wco][wc0 + 8] = wv1;
    };

    stage(0, 0);
    __syncthreads();

    for (int k = 0; k < Kk; ++k) {
        int cb = k & 1;
        if (k < Kk - 1) stage(k + 1, cb ^ 1);

        // GEMM: out[co][px] += W^T[co][c] * S^T[c][px], K=64 per k (2 mfma steps)
        bf16x8 b0 = *(const bf16x8*)&s_S[cb][(wv << 4) + lm][(g << 3)];
        bf16x8 b1 = *(const bf16x8*)&s_S[cb][(wv << 4) + lm][32 + (g << 3)];
#pragma unroll
        for (int f = 0; f < 4; ++f) {
            bf16x8 A0 = *(const bf16x8*)&s_W[cb][(f << 4) + lm][(g << 3)];
            bf16x8 A1 = *(const bf16x8*)&s_W[cb][(f << 4) + lm][32 + (g << 3)];
            acc[f] = __builtin_amdgcn_mfma_f32_16x16x32_bf16(A0, b0, acc[f], 0, 0, 0);
            acc[f] = __builtin_amdgcn_mfma_f32_16x16x32_bf16(A1, b1, acc[f], 0, 0, 0);
        }
        __syncthreads();
    }

    // epilogue: lane l holds D[co = 16f + 4g + r][px = 16wv + lm]
    float* outb = out + (size_t)b * CO * HW + (size_t)y * Ww + x0 + (wv << 4) + lm;
#pragma unroll
    for (int f = 0; f < 4; ++f) {
#pragma unroll
        for (int r = 0; r < 4; ++r) {
            int co = (f << 4) + (g << 2) + r;
            outb[(size_t)co * HW] = acc[f][r] + bias[co];
        }
    }
}

// ---------------- launcher ----------------
extern "C" void kernel_launch(void* const* d_in, const int* in_sizes, int n_in,
                              void* d_out, int out_size, void* d_ws, size_t ws_size,
                              hipStream_t stream)
{
    const float* in   = (const float*)d_in[0];
    const float* offm = (const float*)d_in[1];
    const float* w    = (const float*)d_in[2];
    const float* bias = (const float*)d_in[3];
    float* out = (float*)d_out;

    short* in_t = (short*)d_ws;                          // 8*128*128*64 bf16 = 16 MiB
    short* w_t  = in_t + (size_t)Bn * HW * Cc;           // 9*64*64 bf16 = 72 KiB

    transpose_in_kernel<<<Bn * Hh * 2, 256, 0, stream>>>(in, in_t);
    prep_w_kernel<<<(Kk * CO * Cc + 255) / 256, 256, 0, stream>>>(w, w_t);
    dcn_main_kernel<<<Bn * Hh * 2, 256, 0, stream>>>(in_t, offm, w_t, bias, out);
}

// Round 4
// 59.850 us; speedup vs baseline: 3.3287x; 1.6330x over previous
//
#include <hip/hip_runtime.h>

#define Bn 8
#define Cc 64
#define CO 64
#define Hh 128
#define Ww 128
#define Kk 9
#define HW (Hh*Ww)

typedef __attribute__((ext_vector_type(8))) short bf16x8;
typedef __attribute__((ext_vector_type(4))) float f32x4;

__device__ __forceinline__ short f2bf(float f) {
    unsigned u = __float_as_uint(f);
    u = (u + 0x7FFFu + ((u >> 16) & 1u)) >> 16;   // RNE
    return (short)u;
}
__device__ __forceinline__ float bf2f(short s) {
    return __uint_as_float(((unsigned)(unsigned short)s) << 16);
}

// ---------------- kernel 1: input NCHW fp32 -> NHWC bf16 ----------------
__global__ __launch_bounds__(256) void transpose_in_kernel(
    const float* __restrict__ in, short* __restrict__ in_t)
{
    __shared__ float tile[64 * 65];
    int bid  = blockIdx.x;          // B*H*2 = 2048
    int xblk = bid & 1;
    int row  = bid >> 1;            // b*H + y
    int y    = row & (Hh - 1);
    int b    = row >> 7;
    int x0   = xblk << 6;
    int t    = threadIdx.x;

    int x  = t & 63;
    int cq = t >> 6;
    const float* src = in + (size_t)b * Cc * HW + (size_t)y * Ww + x0;
#pragma unroll
    for (int i = 0; i < 16; ++i) {
        int c = cq * 16 + i;
        tile[c * 65 + x] = src[(size_t)c * HW + x];
    }
    __syncthreads();
    int c2 = t & 63;
    int xq = t >> 6;
    short* dst = in_t + ((size_t)(b * Hh + y) * Ww + x0) * Cc;
#pragma unroll
    for (int i = 0; i < 16; ++i) {
        int xx = xq * 16 + i;
        dst[(size_t)xx * Cc + c2] = f2bf(tile[c2 * 65 + xx]);
    }
}

// ---------------- kernel 2: weight fp32 [co][c][k] -> bf16 [k][co][c] ----------------
__global__ __launch_bounds__(256) void prep_w_kernel(
    const float* __restrict__ w, short* __restrict__ w_t)
{
    int idx = blockIdx.x * 256 + threadIdx.x;
    if (idx < Kk * CO * Cc) {
        int k  = idx >> 12;
        int co = (idx >> 6) & 63;
        int c  = idx & 63;
        w_t[idx] = f2bf(w[((size_t)co * Cc + c) * Kk + k]);
    }
}

// ---------------- kernel 3: fused sample + MFMA implicit GEMM ----------------
// Sampling: 4 lanes per pixel (lane = 4*p_sub + chunk). Each gather instr
// loads one aligned 64B line per pixel -> 16 line-requests/instr (was 64).
__global__ __launch_bounds__(256, 4) void dcn_main_kernel(
    const short* __restrict__ in_t,   // [B][H][W][C] bf16
    const float* __restrict__ offm,   // [B][27][H][W] fp32
    const short* __restrict__ w_t,    // [K][CO][C] bf16
    const float* __restrict__ bias,   // [CO] fp32
    float* __restrict__ out)          // [B][CO][H][W] fp32
{
    __shared__ short s_S[2][64][72];  // sampled bf16 [px][c], pad 72
    __shared__ short s_W[2][64][72];  // weight  bf16 [co][c], pad 72

    int bid  = blockIdx.x;            // 2048
    int xblk = bid & 1;
    int row  = bid >> 1;
    int y    = row & (Hh - 1);
    int b    = row >> 7;
    int x0   = xblk << 6;
    int t    = threadIdx.x;
    int l    = t & 63;
    int wv   = t >> 6;                // wave 0..3
    int p_sub = l >> 2;               // 0..15
    int chunk = l & 3;                // 16B chunk within 64B half-line
    int px   = (wv << 4) + p_sub;     // sampling pixel (wave covers 16 px)

    const float* offb = offm + (size_t)b * 27 * HW + (size_t)y * Ww + x0 + px;
    const short* inb  = in_t + (size_t)b * HW * Cc;

    // W staging indices (256 threads cover 64co x 64c)
    int wco = t >> 2;
    int wc0 = (t & 3) << 4;

    // preload all 27 per-pixel offset scalars into registers (coalesced)
    float offv[Kk][3];
#pragma unroll
    for (int k = 0; k < Kk; ++k) {
        offv[k][0] = offb[(size_t)(2 * k) * HW];
        offv[k][1] = offb[(size_t)(2 * k + 1) * HW];
        offv[k][2] = offb[(size_t)(18 + k) * HW];
    }

    f32x4 acc[4] = {{0.f,0.f,0.f,0.f},{0.f,0.f,0.f,0.f},{0.f,0.f,0.f,0.f},{0.f,0.f,0.f,0.f}};
    int lm = l & 15;   // mfma col select
    int g  = l >> 4;   // mfma k-chunk group

    bf16x8 r[4][2];    // staged corner data: [corner][half]
    float  cw[4];      // corner weights (mask folded)
    bf16x8 wr[2];      // staged weight slice

    auto stage_load = [&](int k) {
        float dy = offv[k][0], dx = offv[k][1], ml = offv[k][2];
        float m  = __builtin_amdgcn_rcpf(1.0f + __expf(-ml));

        float ys = (float)(y + (k / 3) - 1) + dy;
        float xs = (float)(x0 + px + (k % 3) - 1) + dx;
        float yf = floorf(ys), xf = floorf(xs);
        int y0i = (int)yf, x0i = (int)xf;
        float wy = ys - yf, wx = xs - xf;

        bool vy0 = (unsigned)y0i < (unsigned)Hh;
        bool vy1 = (unsigned)(y0i + 1) < (unsigned)Hh;
        bool vx0 = (unsigned)x0i < (unsigned)Ww;
        bool vx1 = (unsigned)(x0i + 1) < (unsigned)Ww;

        int cy0 = min(max(y0i, 0), Hh - 1);
        int cy1 = min(max(y0i + 1, 0), Hh - 1);
        int cx0 = min(max(x0i, 0), Ww - 1);
        int cx1 = min(max(x0i + 1, 0), Ww - 1);

        cw[0] = (vy0 && vx0) ? (1.0f - wy) * (1.0f - wx) * m : 0.0f;
        cw[1] = (vy0 && vx1) ? (1.0f - wy) * wx * m : 0.0f;
        cw[2] = (vy1 && vx0) ? wy * (1.0f - wx) * m : 0.0f;
        cw[3] = (vy1 && vx1) ? wy * wx * m : 0.0f;

        int i00 = cy0 * Ww + cx0, i01 = cy0 * Ww + cx1;
        int i10 = cy1 * Ww + cx0, i11 = cy1 * Ww + cx1;
        int idx0[4] = {i00, i01, i10, i11};

#pragma unroll
        for (int cc = 0; cc < 4; ++cc) {
            // 4 lanes (chunk 0..3) cover one 64B line per instruction
            const short* p = inb + (size_t)idx0[cc] * Cc + (chunk << 3);
            r[cc][0] = *(const bf16x8*)p;          // channels chunk*8   .. +7
            r[cc][1] = *(const bf16x8*)(p + 32);   // channels 32+chunk*8.. +7
        }
        const short* wk = w_t + (size_t)k * (CO * Cc) + 16 * t;
        wr[0] = *(const bf16x8*)(wk);
        wr[1] = *(const bf16x8*)(wk + 8);
    };

    auto stage_finish = [&](int nb) {
        float a0[8], a1[8];
#pragma unroll
        for (int j = 0; j < 8; ++j) { a0[j] = 0.0f; a1[j] = 0.0f; }
#pragma unroll
        for (int cc = 0; cc < 4; ++cc) {
            float w = cw[cc];
#pragma unroll
            for (int j = 0; j < 8; ++j) {
                a0[j] += w * bf2f(r[cc][0][j]);
                a1[j] += w * bf2f(r[cc][1][j]);
            }
        }
        union { bf16x8 v; short s[8]; } o0, o1;
#pragma unroll
        for (int j = 0; j < 8; ++j) { o0.s[j] = f2bf(a0[j]); o1.s[j] = f2bf(a1[j]); }
        *(bf16x8*)&s_S[nb][px][(chunk << 3)]      = o0.v;
        *(bf16x8*)&s_S[nb][px][32 + (chunk << 3)] = o1.v;

        *(bf16x8*)&s_W[nb][wco][wc0]     = wr[0];
        *(bf16x8*)&s_W[nb][wco][wc0 + 8] = wr[1];
    };

    stage_load(0);
    stage_finish(0);
    __syncthreads();

#pragma unroll
    for (int k = 0; k < Kk; ++k) {
        int cb = k & 1;
        if (k < Kk - 1) stage_load(k + 1);   // issue gathers; latency hides under MFMA

        // GEMM: out[co][px] += W^T[co][c] * S^T[c][px], K=64 per k
        bf16x8 b0 = *(const bf16x8*)&s_S[cb][(wv << 4) + lm][(g << 3)];
        bf16x8 b1 = *(const bf16x8*)&s_S[cb][(wv << 4) + lm][32 + (g << 3)];
#pragma unroll
        for (int f = 0; f < 4; ++f) {
            bf16x8 A0 = *(const bf16x8*)&s_W[cb][(f << 4) + lm][(g << 3)];
            bf16x8 A1 = *(const bf16x8*)&s_W[cb][(f << 4) + lm][32 + (g << 3)];
            acc[f] = __builtin_amdgcn_mfma_f32_16x16x32_bf16(A0, b0, acc[f], 0, 0, 0);
            acc[f] = __builtin_amdgcn_mfma_f32_16x16x32_bf16(A1, b1, acc[f], 0, 0, 0);
        }
        if (k < Kk - 1) stage_finish(cb ^ 1);  // vmcnt wait lands after MFMA
        __syncthreads();
    }

    // epilogue: lane l holds D[co = 16f + 4g + r][px = 16wv + lm]
    float* outb = out + (size_t)b * CO * HW + (size_t)y * Ww + x0 + (wv << 4) + lm;
#pragma unroll
    for (int f = 0; f < 4; ++f) {
#pragma unroll
        for (int rr = 0; rr < 4; ++rr) {
            int co = (f << 4) + (g << 2) + rr;
            outb[(size_t)co * HW] = acc[f][rr] + bias[co];
        }
    }
}

// ---------------- launcher ----------------
extern "C" void kernel_launch(void* const* d_in, const int* in_sizes, int n_in,
                              void* d_out, int out_size, void* d_ws, size_t ws_size,
                              hipStream_t stream)
{
    const float* in   = (const float*)d_in[0];
    const float* offm = (const float*)d_in[1];
    const float* w    = (const float*)d_in[2];
    const float* bias = (const float*)d_in[3];
    float* out = (float*)d_out;

    short* in_t = (short*)d_ws;                          // 8*128*128*64 bf16 = 16 MiB
    short* w_t  = in_t + (size_t)Bn * HW * Cc;           // 9*64*64 bf16 = 72 KiB

    transpose_in_kernel<<<Bn * Hh * 2, 256, 0, stream>>>(in, in_t);
    prep_w_kernel<<<(Kk * CO * Cc + 255) / 256, 256, 0, stream>>>(w, w_t);
    dcn_main_kernel<<<Bn * Hh * 2, 256, 0, stream>>>(in_t, offm, w_t, bias, out);
}